// Round 2
// baseline (133.229 us; speedup 1.0000x reference)
//
#include <hip/hip_runtime.h>
#include <hip/hip_bf16.h>

#define NROWS 8192
#define HALFN 4096
#define DIMK  128
#define JC    32              // j-chunks
#define LJ    (NROWS / JC)    // 256 columns per chunk
#define BAND  128             // rows per block in main kernel
#define NBAND (NROWS / BAND)  // 64

typedef __attribute__((ext_vector_type(8))) short short8;
typedef __attribute__((ext_vector_type(4))) float f32x4;

// z is pre-scaled by sqrt(2*log2(e)) so dot(za, zb) = sim * log2(e) * ... :
// exp(sim) = exp(2*dot_orig) = 2^(2*log2e*dot_orig) = 2^(dot_scaled)
#define SQRT_EXPSCALE 1.6986436f      // sqrt(2*log2(e))
#define LN2F          0.69314718f     // 2/(2*log2(e))

static __device__ __forceinline__ float bf2f(unsigned short u) {
    union { float f; unsigned int i; } x;
    x.i = ((unsigned int)u) << 16;
    return x.f;
}

// ---------------- K1: normalize+scale rows, write bf16 [8192][128] ----------
__global__ __launch_bounds__(256) void k_norm(const float* __restrict__ zi,
                                              const float* __restrict__ zj,
                                              unsigned short* __restrict__ znb) {
    const int lane = threadIdx.x & 63;
    const int wave = threadIdx.x >> 6;
    const int row  = blockIdx.x * 4 + wave;
    const float* src = (row < HALFN) ? (zi + (size_t)row * DIMK)
                                     : (zj + (size_t)(row - HALFN) * DIMK);
    float2 v = *reinterpret_cast<const float2*>(src + lane * 2);
    float ss = v.x * v.x + v.y * v.y;
    #pragma unroll
    for (int m = 1; m < 64; m <<= 1) ss += __shfl_xor(ss, m);
    float rn = rsqrtf(ss) * SQRT_EXPSCALE;
    __hip_bfloat16 ha = __float2bfloat16(v.x * rn);
    __hip_bfloat16 hb = __float2bfloat16(v.y * rn);
    ushort2 o;
    o.x = *reinterpret_cast<unsigned short*>(&ha);
    o.y = *reinterpret_cast<unsigned short*>(&hb);
    *reinterpret_cast<ushort2*>(znb + (size_t)row * DIMK + lane * 2) = o;
}

// ---------------- K2: fused sim + exp row-sum (per j-chunk partials) --------
// grid = NBAND*JC = 2048 blocks, 256 threads (4 waves). Each wave owns 32 rows
// (2 x 16-row MFMA fragments) and streams its chunk's 256 columns.
#define TILE_COMPUTE(BUF, JT)                                                  \
    {                                                                          \
        const int j0 = jbase + (JT) * 16;                                      \
        _Pragma("unroll")                                                      \
        for (int rf = 0; rf < 2; ++rf) {                                       \
            f32x4 c = {0.f, 0.f, 0.f, 0.f};                                    \
            _Pragma("unroll")                                                  \
            for (int kk = 0; kk < 4; ++kk)                                     \
                c = __builtin_amdgcn_mfma_f32_16x16x32_bf16(afr[rf][kk],       \
                                                            BUF[kk], c, 0, 0, 0); \
            if (__builtin_expect(j0 == row0 + rf * 16, 0)) {                   \
                _Pragma("unroll")                                              \
                for (int r = 0; r < 4; ++r) {                                  \
                    float e = exp2f(c[r]);                                     \
                    if (rsel == g * 4 + r) e = 0.f; /* mask j == i */          \
                    sacc[rf][r] += e;                                          \
                }                                                              \
            } else {                                                           \
                _Pragma("unroll")                                              \
                for (int r = 0; r < 4; ++r) sacc[rf][r] += exp2f(c[r]);        \
            }                                                                  \
        }                                                                      \
    }

__global__ __launch_bounds__(256) void k_main(const unsigned short* __restrict__ znb,
                                              float* __restrict__ Spart) {
    const int lane = threadIdx.x & 63;
    const int wave = threadIdx.x >> 6;
    const int band = blockIdx.x & (NBAND - 1);
    const int jc   = blockIdx.x >> 6;     // / NBAND==64
    const int row0 = band * BAND + wave * 32;
    const int jbase = jc * LJ;

    const int rsel = lane & 15;   // fragment row/col selector
    const int g    = lane >> 4;   // k-group

    // A fragments: 32 rows; lane: row = row0 + rf*16 + rsel, k = kk*32+g*8..+7
    const unsigned short* arow = znb + (size_t)(row0 + rsel) * DIMK + g * 8;
    short8 afr[2][4];
    #pragma unroll
    for (int rf = 0; rf < 2; ++rf)
        #pragma unroll
        for (int kk = 0; kk < 4; ++kk)
            afr[rf][kk] = *reinterpret_cast<const short8*>(arow + rf * 16 * DIMK + kk * 32);

    float sacc[2][4];
    #pragma unroll
    for (int rf = 0; rf < 2; ++rf)
        #pragma unroll
        for (int r = 0; r < 4; ++r) sacc[rf][r] = 0.f;

    const unsigned short* bbase = znb + (size_t)(jbase + rsel) * DIMK + g * 8;

    // double-buffered B tiles (static indices; unroll-2 to avoid copies)
    short8 bA[4], bB[4];
    #pragma unroll
    for (int kk = 0; kk < 4; ++kk)
        bA[kk] = *reinterpret_cast<const short8*>(bbase + kk * 32);

    for (int jt = 0; jt < LJ / 16; jt += 2) {
        #pragma unroll
        for (int kk = 0; kk < 4; ++kk)
            bB[kk] = *reinterpret_cast<const short8*>(
                bbase + (size_t)(jt + 1) * 16 * DIMK + kk * 32);
        TILE_COMPUTE(bA, jt);
        #pragma unroll
        for (int kk = 0; kk < 4; ++kk)
            bA[kk] = *reinterpret_cast<const short8*>(
                bbase + (size_t)((jt + 2) & (LJ / 16 - 1)) * 16 * DIMK + kk * 32);
        TILE_COMPUTE(bB, jt + 1);
    }

    // Reduce across the 16 lanes of each k-group (16 columns of same rows)
    #pragma unroll
    for (int rf = 0; rf < 2; ++rf)
        #pragma unroll
        for (int r = 0; r < 4; ++r) {
            float v = sacc[rf][r];
            v += __shfl_xor(v, 1);
            v += __shfl_xor(v, 2);
            v += __shfl_xor(v, 4);
            v += __shfl_xor(v, 8);
            sacc[rf][r] = v;
        }
    if (rsel == 0) {
        #pragma unroll
        for (int rf = 0; rf < 2; ++rf) {
            float4 o = make_float4(sacc[rf][0], sacc[rf][1], sacc[rf][2], sacc[rf][3]);
            *reinterpret_cast<float4*>(Spart + (size_t)jc * NROWS + row0 + rf * 16 + g * 4) = o;
        }
    }
}

// ---------------- K3: per-row log(S) - pos, block partials ------------------
// 512 blocks x 256 threads; each 16-lane group owns one row.
__global__ __launch_bounds__(256) void k_rowterm(const unsigned short* __restrict__ znb,
                                                 const float* __restrict__ Spart,
                                                 float* __restrict__ partial) {
    __shared__ float red[16];
    const int lane = threadIdx.x & 63;
    const int wave = threadIdx.x >> 6;
    const int rsel = lane & 15;
    const int g    = lane >> 4;
    const int row  = blockIdx.x * 16 + wave * 4 + g;
    const int p    = (row + HALFN) & (NROWS - 1);

    short8 a = *reinterpret_cast<const short8*>(znb + (size_t)row * DIMK + rsel * 8);
    short8 b = *reinterpret_cast<const short8*>(znb + (size_t)p   * DIMK + rsel * 8);
    float d = 0.f;
    #pragma unroll
    for (int i = 0; i < 8; ++i)
        d += bf2f((unsigned short)a[i]) * bf2f((unsigned short)b[i]);
    float S = Spart[(size_t)rsel * NROWS + row] + Spart[(size_t)(rsel + 16) * NROWS + row];
    #pragma unroll
    for (int m = 1; m < 16; m <<= 1) {
        d += __shfl_xor(d, m);
        S += __shfl_xor(S, m);
    }
    if (rsel == 0) red[wave * 4 + g] = __logf(S) - d * LN2F;
    __syncthreads();
    if (threadIdx.x < 16) {
        float v = red[threadIdx.x];
        #pragma unroll
        for (int m = 1; m < 16; m <<= 1) v += __shfl_xor(v, m);
        if (threadIdx.x == 0) partial[blockIdx.x] = v;
    }
}

// ---------------- K4: final reduce -> loss ----------------------------------
__global__ __launch_bounds__(256) void k_final(const float* __restrict__ partial,
                                               float* __restrict__ out) {
    __shared__ float red[4];
    const int tid = threadIdx.x;
    float s = partial[tid] + partial[tid + 256];
    #pragma unroll
    for (int m = 1; m < 64; m <<= 1) s += __shfl_xor(s, m);
    if ((tid & 63) == 0) red[tid >> 6] = s;
    __syncthreads();
    if (tid == 0)
        out[0] = (red[0] + red[1] + red[2] + red[3]) * (1.0f / (float)NROWS);
}

extern "C" void kernel_launch(void* const* d_in, const int* in_sizes, int n_in,
                              void* d_out, int out_size, void* d_ws, size_t ws_size,
                              hipStream_t stream) {
    const float* zi = (const float*)d_in[0];
    const float* zj = (const float*)d_in[1];
    float* out = (float*)d_out;
    char* ws = (char*)d_ws;

    unsigned short* znb   = (unsigned short*)ws;                        // 2 MB
    float*          Spart = (float*)(ws + (size_t)NROWS * DIMK * 2);    // 1 MB
    float*          part  = (float*)(ws + (size_t)NROWS * DIMK * 2
                                        + (size_t)JC * NROWS * 4);      // 2 KB

    k_norm   <<<NROWS / 4, 256, 0, stream>>>(zi, zj, znb);
    k_main   <<<NBAND * JC, 256, 0, stream>>>(znb, Spart);
    k_rowterm<<<NROWS / 16, 256, 0, stream>>>(znb, Spart, part);
    k_final  <<<1, 256, 0, stream>>>(part, out);
}